// Round 1
// baseline (981.071 us; speedup 1.0000x reference)
//
#include <hip/hip_runtime.h>
#include <cfloat>
#include <math.h>

#define N_NODES 500000
#define C_DIM   256
#define R_DIM   64
#define G_NUM   4096

// ---------------------------------------------------------------------------
// Kernel 1: segment max + sum pooling. One block per graph g.
// batch is sorted -> binary search the [start,end) row range.
// 256 threads = 64 channel-quads (float4) x 4 row-groups.
// ---------------------------------------------------------------------------
__global__ __launch_bounds__(256) void seg_pool_kernel(
    const float* __restrict__ x, const int* __restrict__ batch,
    float* __restrict__ gmax, float* __restrict__ gsum) {
  const int g = blockIdx.x;

  // lower_bound(batch, g) and lower_bound(batch, g+1), done redundantly per thread
  int lo = 0, hi = N_NODES;
  while (lo < hi) { int mid = (lo + hi) >> 1; if (batch[mid] < g) lo = mid + 1; else hi = mid; }
  const int start = lo;
  hi = N_NODES;
  while (lo < hi) { int mid = (lo + hi) >> 1; if (batch[mid] <= g) lo = mid + 1; else hi = mid; }
  const int end = lo;

  const int tid = threadIdx.x;
  const int c4  = tid & 63;   // which float4 of the 256-channel row
  const int rg  = tid >> 6;   // row-group 0..3

  float4 vmax = make_float4(-FLT_MAX, -FLT_MAX, -FLT_MAX, -FLT_MAX);
  float4 vsum = make_float4(0.f, 0.f, 0.f, 0.f);

  const float4* xr = (const float4*)x;
  for (int n = start + rg; n < end; n += 4) {
    float4 v = xr[(size_t)n * 64 + c4];
    vmax.x = fmaxf(vmax.x, v.x); vmax.y = fmaxf(vmax.y, v.y);
    vmax.z = fmaxf(vmax.z, v.z); vmax.w = fmaxf(vmax.w, v.w);
    vsum.x += v.x; vsum.y += v.y; vsum.z += v.z; vsum.w += v.w;
  }

  __shared__ float4 smax[4][64];
  __shared__ float4 ssum[4][64];
  smax[rg][c4] = vmax;
  ssum[rg][c4] = vsum;
  __syncthreads();

  if (rg == 0) {
    for (int i = 1; i < 4; ++i) {
      float4 m = smax[i][c4];
      float4 s = ssum[i][c4];
      vmax.x = fmaxf(vmax.x, m.x); vmax.y = fmaxf(vmax.y, m.y);
      vmax.z = fmaxf(vmax.z, m.z); vmax.w = fmaxf(vmax.w, m.w);
      vsum.x += s.x; vsum.y += s.y; vsum.z += s.z; vsum.w += s.w;
    }
    if (start == end) vmax = make_float4(0.f, 0.f, 0.f, 0.f);  // torch_scatter empty-seg rule
    ((float4*)gmax)[(size_t)g * 64 + c4] = vmax;
    ((float4*)gsum)[(size_t)g * 64 + c4] = vsum;
  }
}

// ---------------------------------------------------------------------------
// Kernel 2: y[g] = sigmoid( W2 * ( relu(W1*zmax) + relu(W1*zsum) ) )
// One block (256 thr) per graph. w1:[R,C] row-major, w2:[C,R] row-major.
// ---------------------------------------------------------------------------
__global__ __launch_bounds__(256) void mlp_kernel(
    const float* __restrict__ gmax, const float* __restrict__ gsum,
    const float* __restrict__ w1, const float* __restrict__ w2,
    float* __restrict__ y) {
  const int g   = blockIdx.x;
  const int tid = threadIdx.x;

  __shared__ float zm[C_DIM];
  __shared__ float zs[C_DIM];
  __shared__ float red_m[256];
  __shared__ float red_s[256];
  __shared__ float hs[R_DIM];

  zm[tid] = gmax[(size_t)g * C_DIM + tid];
  zs[tid] = gsum[(size_t)g * C_DIM + tid];
  __syncthreads();

  // Layer 1: h[r] = relu(dot(zm,w1[r])) + relu(dot(zs,w1[r]))
  // thread (r, part): partial dot over c in [part*64, part*64+64)
  const int r    = tid & 63;
  const int part = tid >> 6;
  float pm = 0.f, ps = 0.f;
  const float* w1r = w1 + (size_t)r * C_DIM + part * 64;
  const float* zmp = zm + part * 64;
  const float* zsp = zs + part * 64;
#pragma unroll 8
  for (int c = 0; c < 64; ++c) {
    float w = w1r[c];
    pm += w * zmp[c];   // same LDS address across the wave -> broadcast
    ps += w * zsp[c];
  }
  red_m[tid] = pm;
  red_s[tid] = ps;
  __syncthreads();
  if (part == 0) {
    float am = pm + red_m[64 + r] + red_m[128 + r] + red_m[192 + r];
    float as = ps + red_s[64 + r] + red_s[128 + r] + red_s[192 + r];
    hs[r] = fmaxf(am, 0.f) + fmaxf(as, 0.f);
  }
  __syncthreads();

  // Layer 2 + sigmoid: thread tid = channel c; w2 row c is 64 contiguous floats
  float acc = 0.f;
  const float4* w2c = (const float4*)(w2 + (size_t)tid * R_DIM);
#pragma unroll
  for (int q = 0; q < R_DIM / 4; ++q) {
    float4 w = w2c[q];
    acc += w.x * hs[4 * q + 0] + w.y * hs[4 * q + 1] +
           w.z * hs[4 * q + 2] + w.w * hs[4 * q + 3];
  }
  y[(size_t)g * C_DIM + tid] = 1.f / (1.f + expf(-acc));
}

// ---------------------------------------------------------------------------
// Kernel 3: out = x * y[batch].  One float4 per thread; a 64-lane wave covers
// exactly one 256-channel row, so batch[n] is a wave-broadcast load.
// ---------------------------------------------------------------------------
__global__ __launch_bounds__(256) void apply_kernel(
    const float* __restrict__ x, const int* __restrict__ batch,
    const float* __restrict__ y, float* __restrict__ out) {
  const long long idx = (long long)blockIdx.x * 256 + threadIdx.x;  // float4 index
  if (idx >= (long long)N_NODES * 64) return;
  const int n   = (int)(idx >> 6);
  const int rem = (int)(idx & 63);
  const int b   = batch[n];
  float4 xv = ((const float4*)x)[idx];
  float4 yv = ((const float4*)y)[(size_t)b * 64 + rem];
  float4 o;
  o.x = xv.x * yv.x; o.y = xv.y * yv.y; o.z = xv.z * yv.z; o.w = xv.w * yv.w;
  ((float4*)out)[idx] = o;
}

extern "C" void kernel_launch(void* const* d_in, const int* in_sizes, int n_in,
                              void* d_out, int out_size, void* d_ws, size_t ws_size,
                              hipStream_t stream) {
  const float* x     = (const float*)d_in[0];
  const int*   batch = (const int*)d_in[1];
  const float* w1    = (const float*)d_in[2];
  const float* w2    = (const float*)d_in[3];
  float* out = (float*)d_out;

  float* gmax = (float*)d_ws;                       // [G, C]  4 MB
  float* gsum = gmax + (size_t)G_NUM * C_DIM;       // [G, C]  4 MB
  float* y    = gsum + (size_t)G_NUM * C_DIM;       // [G, C]  4 MB

  seg_pool_kernel<<<G_NUM, 256, 0, stream>>>(x, batch, gmax, gsum);
  mlp_kernel<<<G_NUM, 256, 0, stream>>>(gmax, gsum, w1, w2, y);

  const int n4 = N_NODES * (C_DIM / 4);             // 32M float4
  apply_kernel<<<(n4 + 255) / 256, 256, 0, stream>>>(x, batch, y, out);
}